// Round 1
// 412.807 us; speedup vs baseline: 1.0482x; 1.0482x over previous
//
#include <hip/hip_runtime.h>

// PoolHiddenNet round 9: FUSE prep's A-conversion into the GEMM.
// r8 evidence: pool_mfma6 139us is neither HBM-bound (6.7%) nor MFMA-bound (19%),
// and the remaining wall time is prep2's 341 MB fp32->bf16 round-trip + kernel
// serialization. This round eliminates Abf entirely:
//  - fused kernel FM=64 x FN=256 (3200 blocks, 4 waves, per-wave 64x64 = r5's
//    exact proven MFMA/swizzle body): A staged fp32->bf16 through registers
//    (T14 split: load after barrier, convert+ds_write before next barrier),
//    B staged via proven pre-swizzled global_load_lds dbuf.
//  - emb columns (K=512..639) computed inline from Ws/bs (L1-resident).
//  - col-sibling blocks (same rowTile) adjacent + same XCD => 2nd fp32 A read
//    hits L2; effective A traffic ~210 MB once, not 341 MB round-trip.
//  - prep3 shrinks to segArr + relA + WmT transpose (480 blocks, ~5us).
// LDS 45 KB/block + __launch_bounds__(256,3) targets 3 blocks/CU (was 2.2).

typedef __bf16 bf16x8 __attribute__((ext_vector_type(8)));
typedef float floatx4 __attribute__((ext_vector_type(4)));

constexpr int NR = 102400;
constexpr int NG = 2048;
constexpr int E  = 128;
constexpr int H  = 512;
constexpr int KD = 640;
// fallback kernel tile (round-2 kernel, unchanged)
constexpr int BM = 128, BN = 128, BK = 32;
// fused kernel tile
constexpr int FM = 64, FN = 256;
constexpr int NKT = KD / BK;   // 20
constexpr int KH  = H / BK;    // 16: first emb k-tile

__device__ inline unsigned short f2bf(float f) {
    unsigned u = __float_as_uint(f);
    u += 0x7FFF + ((u >> 16) & 1u);   // RNE (finite inputs)
    return (unsigned short)(u >> 16);
}

// pack two fp32 -> bf16x2, round-half-up: 2x v_add + 1x v_perm_b32
__device__ inline unsigned pk2(float lo, float hi) {
    return __builtin_amdgcn_perm(__float_as_uint(hi) + 0x8000u,
                                 __float_as_uint(lo) + 0x8000u, 0x07060302u);
}

__device__ inline void async16(const void* g, void* l) {
    __builtin_amdgcn_global_load_lds(
        (const __attribute__((address_space(1))) unsigned int*)g,
        (__attribute__((address_space(3))) unsigned int*)l, 16, 0, 0);
}

// ---------------- prep: segArr + relA (400 blocks) + WmT transpose (80) ----------------
__global__ __launch_bounds__(256) void prep3(
    const float* __restrict__ pos, const int* __restrict__ sse,
    const float* __restrict__ Wm, unsigned short* __restrict__ WmT,
    int* __restrict__ segArr, float* __restrict__ relA)
{
    const int b = blockIdx.x;
    const int t = threadIdx.x;
    __shared__ float tile[64][65];
    if (b < 400) {
        if (!segArr) return;
        const int i = b * 256 + t;
        int l = 0, r = NG + 1;
        while (l < r) { int m = (l + r) >> 1; if (sse[m] <= i) l = m + 1; else r = m; }
        const int g = l - 1;
        segArr[i] = g;
        const int a = sse[g];
        relA[2 * i + 0] = pos[2 * i + 0] - pos[2 * a + 0];
        relA[2 * i + 1] = pos[2 * i + 1] - pos[2 * a + 1];
    } else {
        const int bb = b - 400;             // [0,80): Wm (640x512) -> WmT (512x640) bf16
        const int kb = (bb % 10) * 64, nb = (bb / 10) * 64;
        const int tx = t & 63, tq = t >> 6;
#pragma unroll
        for (int i = 0; i < 16; ++i) {
            const int k = tq * 16 + i;
            tile[k][tx] = Wm[(size_t)(kb + k) * H + nb + tx];
        }
        __syncthreads();
#pragma unroll
        for (int i = 0; i < 16; ++i) {
            const int n = tq * 16 + i;
            WmT[(size_t)(nb + n) * KD + kb + tx] = f2bf(tile[tx][n]);
        }
    }
}

// ---------------- fused: fp32 A staging + GEMM + segment-max ----------------
__global__ __launch_bounds__(256, 3) void pool_fused(
    const float* __restrict__ hist_enc,       // (NR, 512) fp32
    const int*   __restrict__ sse,
    const int*   __restrict__ segArr,         // (NR,)
    const float* __restrict__ relA,           // (NR, 2) fp32
    const float* __restrict__ Ws,             // (2, 128)
    const float* __restrict__ bs,             // (128,)
    const unsigned short* __restrict__ WmT,   // (512, 640) bf16
    const float* __restrict__ bm,             // (512,)
    float*       __restrict__ out)            // (2048, 512) fp32, zeroed
{
    __shared__ __attribute__((aligned(16))) unsigned short As2[2][FM * BK]; // 2 x 4 KB
    __shared__ __attribute__((aligned(16))) unsigned short Bs2[2][FN * BK]; // 2 x 16 KB
    __shared__ float2 relRow[FM];
    __shared__ int segRow[FM];
    __shared__ int bnd[3];
    __shared__ int Pmax[4][FN + 4];

    const int t   = threadIdx.x;
    const int bid = blockIdx.x;
    // XCD swizzle: the 2 column-siblings of a rowTile share bid%8 (same XCD,
    // adjacent dispatch) so the second fp32 A-tile read is an L2 hit.
    const int rowTile = (bid >> 4) * 8 + (bid & 7);   // [0,1600)
    const int colTile = (bid >> 3) & 1;               // [0,2)
    const int rowBase = rowTile * FM;
    const int cTile   = colTile * FN;

    const int lane  = t & 63;
    const int wv    = t >> 6;          // 4 waves, wave grid 1x4
    const int wc    = wv * 64;
    const int lcol  = lane & 15;
    const int lquad = lane >> 4;

    // ---- B staging: wave wv stages rows [wv*64, wv*64+64), 4 async16/kt ----
    // source chunk XOR-swizzled (proven r5 scheme) so ds_read_b128 frags are ~2-way.
    const int sR   = lane >> 2;
    const int phys = lane & 3;
    const unsigned short* gB[4];
#pragma unroll
    for (int s = 0; s < 4; ++s) {
        const int row = wv * 64 + s * 16 + sR;
        const int cl  = phys ^ ((row >> 1) & 3);
        gB[s] = WmT + (size_t)(cTile + row) * KD + cl * 8;
    }
    auto issueB = [&](int kt, int buf) {
        const int ko = kt * BK;
#pragma unroll
        for (int s = 0; s < 4; ++s)
            async16(gB[s] + ko, &Bs2[buf][wv * 2048 + s * 512]);
    };

    // ---- A staging (reg path): thread t owns row t>>2, 8-elem chunk t&3 ----
    const int arow = t >> 2, ach = t & 3;
    const int aoff = arow * BK + (ach ^ ((arow >> 1) & 3)) * 8;  // swizzled LDS slot
    const float* gA = hist_enc + (size_t)(rowBase + arow) * H + ach * 8;

    issueB(0, 0);

    // ---- prologue ----
    if (t < FM) {
        segRow[t] = segArr[rowBase + t];
        relRow[t] = *(const float2*)&relA[2 * (rowBase + t)];
    }
    if (t >= FM && t < FM + 3) bnd[t - FM] = FM;
    for (int idx = t; idx < 4 * (FN + 4); idx += 256) ((int*)Pmax)[idx] = 0;

    // stage A tile 0 (always hist range)
    {
        const float4 h0 = *(const float4*)(gA);
        const float4 h1 = *(const float4*)(gA + 4);
        uint4 u;
        u.x = pk2(h0.x, h0.y); u.y = pk2(h0.z, h0.w);
        u.z = pk2(h1.x, h1.y); u.w = pk2(h1.z, h1.w);
        *(uint4*)&As2[0][aoff] = u;
    }
    __syncthreads();
    if (t < FM - 1) {
        const int s0 = segRow[t], s1 = segRow[t + 1];
        if (s1 != s0) bnd[s1 - segRow[0] - 1] = t + 1;   // visible after next barrier
    }

    floatx4 acc[4][4];
#pragma unroll
    for (int m = 0; m < 4; ++m)
#pragma unroll
        for (int n = 0; n < 4; ++n) acc[m][n] = (floatx4){0.f, 0.f, 0.f, 0.f};

    // ---- K loop: distance-1 dbuf DMA for B; T14 reg-staged fp32->bf16 for A ----
    for (int kt = 0; kt < NKT; ++kt) {
        __syncthreads();                     // drains tile kt's DMA + A ds_write
        const int nxt = kt + 1;
        float4 w0a, w0b, w1a, w1b, ba, bb;
        float r0 = 0.f, r1 = 0.f;
        bool hist = true;
        if (nxt < NKT) {
            issueB(nxt, nxt & 1);
            if (nxt < KH) {
                w0a = *(const float4*)(gA + nxt * BK);
                w0b = *(const float4*)(gA + nxt * BK + 4);
            } else {                          // emb columns: relu(rel @ Ws + bs)
                hist = false;
                const int e0 = nxt * BK - H + ach * 8;
                w0a = *(const float4*)&Ws[e0];     w0b = *(const float4*)&Ws[e0 + 4];
                w1a = *(const float4*)&Ws[E + e0]; w1b = *(const float4*)&Ws[E + e0 + 4];
                ba  = *(const float4*)&bs[e0];     bb  = *(const float4*)&bs[e0 + 4];
                const float2 rr = relRow[arow];
                r0 = rr.x; r1 = rr.y;
            }
        }

        const unsigned short* A = As2[kt & 1];
        const unsigned short* B = Bs2[kt & 1];
        bf16x8 af[4], bfr[4];
#pragma unroll
        for (int mt = 0; mt < 4; ++mt) {
            const int R  = mt * 16 + lcol;
            const int pc = lquad ^ ((R >> 1) & 3);
            af[mt] = *(const bf16x8*)&A[R * BK + pc * 8];
        }
#pragma unroll
        for (int nt = 0; nt < 4; ++nt) {
            const int R  = wc + nt * 16 + lcol;
            const int pc = lquad ^ ((R >> 1) & 3);
            bfr[nt] = *(const bf16x8*)&B[R * BK + pc * 8];
        }
#pragma unroll
        for (int mt = 0; mt < 4; ++mt)
#pragma unroll
            for (int nt = 0; nt < 4; ++nt)
                acc[mt][nt] = __builtin_amdgcn_mfma_f32_16x16x32_bf16(af[mt], bfr[nt], acc[mt][nt], 0, 0, 0);

        if (nxt < NKT) {                     // convert + write into the other buffer
            uint4 u;
            if (hist) {
                u.x = pk2(w0a.x, w0a.y); u.y = pk2(w0a.z, w0a.w);
                u.z = pk2(w0b.x, w0b.y); u.w = pk2(w0b.z, w0b.w);
            } else {
                const float v0 = fmaxf(r0 * w0a.x + r1 * w1a.x + ba.x, 0.f);
                const float v1 = fmaxf(r0 * w0a.y + r1 * w1a.y + ba.y, 0.f);
                const float v2 = fmaxf(r0 * w0a.z + r1 * w1a.z + ba.z, 0.f);
                const float v3 = fmaxf(r0 * w0a.w + r1 * w1a.w + ba.w, 0.f);
                const float v4 = fmaxf(r0 * w0b.x + r1 * w1b.x + bb.x, 0.f);
                const float v5 = fmaxf(r0 * w0b.y + r1 * w1b.y + bb.y, 0.f);
                const float v6 = fmaxf(r0 * w0b.z + r1 * w1b.z + bb.z, 0.f);
                const float v7 = fmaxf(r0 * w0b.w + r1 * w1b.w + bb.w, 0.f);
                u.x = pk2(v0, v1); u.y = pk2(v2, v3);
                u.z = pk2(v4, v5); u.w = pk2(v6, v7);
            }
            *(uint4*)&As2[nxt & 1][aoff] = u;
        }
    }

    // ---- epilogue: bias + relu + segment-max (proven; 64 rows span <=3 segs) ----
    const int b0 = bnd[0], b1 = bnd[1], b2 = bnd[2];
    const int segBase = segRow[0];

#pragma unroll
    for (int nt = 0; nt < 4; ++nt) {
        const int col  = wc + nt * 16 + lcol;
        const float bias = bm[cTile + col];
        float pm[4] = {0.f, 0.f, 0.f, 0.f};
#pragma unroll
        for (int mt = 0; mt < 4; ++mt) {
#pragma unroll
            for (int r = 0; r < 4; ++r) {
                const int lr = mt * 16 + lquad * 4 + r;
                const int ls = (lr >= b0) + (lr >= b1) + (lr >= b2);
                const float v = fmaxf(acc[mt][nt][r] + bias, 0.f);
                pm[ls] = fmaxf(pm[ls], v);
            }
        }
#pragma unroll
        for (int ls = 0; ls < 4; ++ls)
            if (pm[ls] > 0.f)
                atomicMax(&Pmax[ls][col], __float_as_int(pm[ls]));
    }
    __syncthreads();

    for (int idx = t; idx < 4 * FN; idx += 256) {
        const int ls = idx >> 8, col = idx & (FN - 1);
        if (ls > 0 && bnd[ls - 1] >= FM) continue;
        const int seg = segBase + ls;
        const int v   = Pmax[ls][col];
        const int gs  = sse[seg], ge = sse[seg + 1];
        float* dst = &out[(size_t)seg * H + cTile + col];
        if (gs >= rowBase && ge <= rowBase + FM) {
            *dst = __int_as_float(v);
        } else {
            atomicMax((int*)dst, v);
        }
    }
}

// ---------------- fallback (round-2 kernel; only if ws too small) ----------------
constexpr int LDAF = 40;
__global__ __launch_bounds__(256) void pool_mfma_fb(
    const float* __restrict__ hist_enc, const float* __restrict__ pos,
    const int* __restrict__ sse, const float* __restrict__ Ws,
    const float* __restrict__ bs, const unsigned short* __restrict__ WmT,
    const float* __restrict__ bm, float* __restrict__ out)
{
    __shared__ __attribute__((aligned(16))) unsigned short As[BM][LDAF];
    __shared__ __attribute__((aligned(16))) unsigned short Bs[BN][LDAF];
    __shared__ float relRow[BM][2];
    __shared__ int   segRow[BM];
    __shared__ int   bnd[3];
    __shared__ int   Pmax[4][BN + 4];

    const int t = threadIdx.x;
    const int cTile = blockIdx.x * BN;
    const int rowBase = blockIdx.y * BM;

    if (t < BM) {
        const int i = rowBase + t;
        int l = 0, r = NG + 1;
        while (l < r) { int m = (l + r) >> 1; if (sse[m] <= i) l = m + 1; else r = m; }
        const int g = l - 1;
        segRow[t] = g;
        const int a = sse[g];
        relRow[t][0] = pos[2 * i + 0] - pos[2 * a + 0];
        relRow[t][1] = pos[2 * i + 1] - pos[2 * a + 1];
    }
    if (t >= BM && t < BM + 3) bnd[t - BM] = BM;
    for (int idx = t; idx < 4 * (BN + 4); idx += 256) ((int*)Pmax)[idx] = 0;
    __syncthreads();
    if (t < BM - 1) {
        const int s0 = segRow[t], s1 = segRow[t + 1];
        if (s1 != s0) bnd[s1 - segRow[0] - 1] = t + 1;
    }

    const int lane = t & 63, wv = t >> 6;
    const int wr = (wv >> 1) * 64, wc = (wv & 1) * 64;
    const int lcol = lane & 15, lquad = lane >> 4;

    floatx4 acc[4][4];
#pragma unroll
    for (int m = 0; m < 4; ++m)
#pragma unroll
        for (int n = 0; n < 4; ++n) acc[m][n] = (floatx4){0.f, 0.f, 0.f, 0.f};

    for (int kt = 0; kt < KD / BK; ++kt) {
        const int k0 = kt * BK;
        float4 av[4]; uint4 bv[2];
        if (k0 < H) {
#pragma unroll
            for (int i = 0; i < 4; ++i) {
                const int idx = i * 256 + t;
                const int row = idx >> 3, kq = (idx & 7) * 4;
                av[i] = *(const float4*)&hist_enc[(size_t)(rowBase + row) * H + k0 + kq];
            }
        } else {
#pragma unroll
            for (int i = 0; i < 4; ++i) {
                const int idx = i * 256 + t;
                const int row = idx >> 3, kq = (idx & 7) * 4;
                const int e = k0 - H + kq;
                const float4 w0 = *(const float4*)&Ws[e];
                const float4 w1 = *(const float4*)&Ws[E + e];
                const float4 b4 = *(const float4*)&bs[e];
                const float r0 = relRow[row][0], r1 = relRow[row][1];
                av[i].x = fmaxf(r0 * w0.x + r1 * w1.x + b4.x, 0.f);
                av[i].y = fmaxf(r0 * w0.y + r1 * w1.y + b4.y, 0.f);
                av[i].z = fmaxf(r0 * w0.z + r1 * w1.z + b4.z, 0.f);
                av[i].w = fmaxf(r0 * w0.w + r1 * w1.w + b4.w, 0.f);
            }
        }
#pragma unroll
        for (int i = 0; i < 2; ++i) {
            const int idx = i * 256 + t;
            const int n = idx >> 2, q = idx & 3;
            bv[i] = *(const uint4*)&WmT[(size_t)(cTile + n) * KD + k0 + q * 8];
        }
        __syncthreads();
#pragma unroll
        for (int i = 0; i < 4; ++i) {
            const int idx = i * 256 + t;
            const int row = idx >> 3, kq = (idx & 7) * 4;
            ushort4 p;
            p.x = f2bf(av[i].x); p.y = f2bf(av[i].y);
            p.z = f2bf(av[i].z); p.w = f2bf(av[i].w);
            *(ushort4*)&As[row][kq] = p;
        }
#pragma unroll
        for (int i = 0; i < 2; ++i) {
            const int idx = i * 256 + t;
            const int n = idx >> 2, q = idx & 3;
            *(uint4*)&Bs[n][q * 8] = bv[i];
        }
        __syncthreads();

        bf16x8 af[4], bfr[4];
#pragma unroll
        for (int mt = 0; mt < 4; ++mt)
            af[mt] = *(const bf16x8*)&As[wr + mt * 16 + lcol][lquad * 8];
#pragma unroll
        for (int nt = 0; nt < 4; ++nt)
            bfr[nt] = *(const bf16x8*)&Bs[wc + nt * 16 + lcol][lquad * 8];
#pragma unroll
        for (int mt = 0; mt < 4; ++mt)
#pragma unroll
            for (int nt = 0; nt < 4; ++nt)
                acc[mt][nt] = __builtin_amdgcn_mfma_f32_16x16x32_bf16(af[mt], bfr[nt], acc[mt][nt], 0, 0, 0);
    }

    const int b0 = bnd[0], b1 = bnd[1], b2 = bnd[2];
    const int segBase = segRow[0];
#pragma unroll
    for (int nt = 0; nt < 4; ++nt) {
        const int col = wc + nt * 16 + lcol;
        const float bias = bm[cTile + col];
        float pm[4] = {0.f, 0.f, 0.f, 0.f};
#pragma unroll
        for (int mt = 0; mt < 4; ++mt) {
#pragma unroll
            for (int r = 0; r < 4; ++r) {
                const int lr = wr + mt * 16 + lquad * 4 + r;
                const int ls = (lr >= b0) + (lr >= b1) + (lr >= b2);
                const float v = fmaxf(acc[mt][nt][r] + bias, 0.f);
                pm[ls] = fmaxf(pm[ls], v);
            }
        }
#pragma unroll
        for (int ls = 0; ls < 4; ++ls)
            if (pm[ls] > 0.f) atomicMax(&Pmax[ls][col], __float_as_int(pm[ls]));
    }
    __syncthreads();
    for (int idx = t; idx < 4 * BN; idx += 256) {
        const int ls = idx >> 7, col = idx & 127;
        if (ls > 0 && bnd[ls - 1] >= BM) continue;
        const int seg = segBase + ls;
        const int v = Pmax[ls][col];
        const int gs = sse[seg], ge = sse[seg + 1];
        float* dst = &out[(size_t)seg * H + cTile + col];
        if (gs >= rowBase && ge <= rowBase + BM) *dst = __int_as_float(v);
        else atomicMax((int*)dst, v);
    }
}

extern "C" void kernel_launch(void* const* d_in, const int* in_sizes, int n_in,
                              void* d_out, int out_size, void* d_ws, size_t ws_size,
                              hipStream_t stream) {
    const float* hist_enc = (const float*)d_in[0];
    const float* pos      = (const float*)d_in[1];
    const int*   sse      = (const int*)  d_in[2];
    const float* Ws       = (const float*)d_in[3];
    const float* bs       = (const float*)d_in[4];
    const float* Wm       = (const float*)d_in[5];
    const float* bm       = (const float*)d_in[6];
    float*       out      = (float*)d_out;

    const size_t needWmT = (size_t)H * KD * 2;     // 655,360 B
    const size_t needSeg = (size_t)NR * 4;         // 409,600 B
    const size_t needRel = (size_t)NR * 2 * 4;     // 819,200 B
    unsigned short* WmT  = (unsigned short*)d_ws;
    int*            segA = (int*)  ((char*)d_ws + needWmT);
    float*          relA = (float*)((char*)d_ws + needWmT + needSeg);

    hipMemsetAsync(out, 0, (size_t)out_size * sizeof(float), stream);

    if (ws_size >= needWmT + needSeg + needRel) {
        prep3<<<480, 256, 0, stream>>>(pos, sse, Wm, WmT, segA, relA);
        pool_fused<<<3200, 256, 0, stream>>>(hist_enc, sse, segA, relA, Ws, bs, WmT, bm, out);
    } else {
        prep3<<<480, 256, 0, stream>>>(pos, sse, Wm, WmT, nullptr, nullptr);
        pool_mfma_fb<<<dim3(H / BN, NR / BM), 256, 0, stream>>>(hist_enc, pos, sse, Ws, bs, WmT, bm, out);
    }
}

// Round 2
// 411.735 us; speedup vs baseline: 1.0509x; 1.0026x over previous
//
#include <hip/hip_runtime.h>

// PoolHiddenNet round 10: fused A-conversion kept, geometry restored to the
// proven r5/r8 shape (BM=128 x BN=128, 2x2 waves, 3200 blocks, 4 col-siblings
// per XCD), plus distance-2 register prefetch for the fp32 A path.
// r9 evidence: FM=64/FN=256 fused kernel ran 199us at MfmaUtil 13.5% --
// interval grew ~580cy = one exposed L3 latency (A loads consumed ~400cy after
// issue) and B staging bytes per MFMA doubled. This round:
//  - A tile kt+2 fp32 loads issued at iter kt, drained by barrier kt+1,
//    consumed at kt+1's convert+ds_write: full-interval in-flight window.
//  - B DMA distance-1 barrier-drained (r6/r7: counted-vmcnt regressed here).
//  - emb tiles (4/20) computed at write time from L1-resident Ws/bs.
//  - LDS 36KB -> 4 blocks/CU; __launch_bounds__(256,4) caps VGPR at 128.

typedef __bf16 bf16x8 __attribute__((ext_vector_type(8)));
typedef float floatx4 __attribute__((ext_vector_type(4)));

constexpr int NR = 102400;
constexpr int NG = 2048;
constexpr int E  = 128;
constexpr int H  = 512;
constexpr int KD = 640;
constexpr int BM = 128, BN = 128, BK = 32;
constexpr int NKT = KD / BK;   // 20
constexpr int KH  = H / BK;    // 16: first emb k-tile

__device__ inline unsigned short f2bf(float f) {
    unsigned u = __float_as_uint(f);
    u += 0x7FFF + ((u >> 16) & 1u);   // RNE (finite inputs)
    return (unsigned short)(u >> 16);
}

// pack two fp32 -> bf16x2, round-half-up: 2x v_add + 1x v_perm_b32
__device__ inline unsigned pk2(float lo, float hi) {
    return __builtin_amdgcn_perm(__float_as_uint(hi) + 0x8000u,
                                 __float_as_uint(lo) + 0x8000u, 0x07060302u);
}

__device__ inline void async16(const void* g, void* l) {
    __builtin_amdgcn_global_load_lds(
        (const __attribute__((address_space(1))) unsigned int*)g,
        (__attribute__((address_space(3))) unsigned int*)l, 16, 0, 0);
}

// ---------------- prep: segArr + relA (400 blocks) + WmT transpose (80) ----------------
__global__ __launch_bounds__(256) void prep3(
    const float* __restrict__ pos, const int* __restrict__ sse,
    const float* __restrict__ Wm, unsigned short* __restrict__ WmT,
    int* __restrict__ segArr, float* __restrict__ relA)
{
    const int b = blockIdx.x;
    const int t = threadIdx.x;
    __shared__ float tile[64][65];
    if (b < 400) {
        if (!segArr) return;
        const int i = b * 256 + t;
        int l = 0, r = NG + 1;
        while (l < r) { int m = (l + r) >> 1; if (sse[m] <= i) l = m + 1; else r = m; }
        const int g = l - 1;
        segArr[i] = g;
        const int a = sse[g];
        relA[2 * i + 0] = pos[2 * i + 0] - pos[2 * a + 0];
        relA[2 * i + 1] = pos[2 * i + 1] - pos[2 * a + 1];
    } else {
        const int bb = b - 400;             // [0,80): Wm (640x512) -> WmT (512x640) bf16
        const int kb = (bb % 10) * 64, nb = (bb / 10) * 64;
        const int tx = t & 63, tq = t >> 6;
#pragma unroll
        for (int i = 0; i < 16; ++i) {
            const int k = tq * 16 + i;
            tile[k][tx] = Wm[(size_t)(kb + k) * H + nb + tx];
        }
        __syncthreads();
#pragma unroll
        for (int i = 0; i < 16; ++i) {
            const int n = tq * 16 + i;
            WmT[(size_t)(nb + n) * KD + kb + tx] = f2bf(tile[tx][n]);
        }
    }
}

// ---------------- fused: fp32 A staging (dist-2) + GEMM + segment-max ----------------
__global__ __launch_bounds__(256, 4) void pool_fused2(
    const float* __restrict__ hist_enc,       // (NR, 512) fp32
    const int*   __restrict__ sse,
    const int*   __restrict__ segArr,         // (NR,)
    const float* __restrict__ relA,           // (NR, 2) fp32
    const float* __restrict__ Ws,             // (2, 128)
    const float* __restrict__ bs,             // (128,)
    const unsigned short* __restrict__ WmT,   // (512, 640) bf16
    const float* __restrict__ bm,             // (512,)
    float*       __restrict__ out)            // (2048, 512) fp32, zeroed
{
    __shared__ __attribute__((aligned(16))) unsigned short As2[2][BM * BK]; // 2 x 8 KB
    __shared__ __attribute__((aligned(16))) unsigned short Bs2[2][BN * BK]; // 2 x 8 KB
    __shared__ float2 relRow[BM];
    __shared__ int segRow[BM];
    __shared__ int bnd[3];
    __shared__ int Pmax[4][BN + 4];

    const int t   = threadIdx.x;
    const int bid = blockIdx.x;
    // XCD swizzle (r8-proven): 4 column-siblings of a rowTile share bid%8.
    const int rowTile = (bid >> 5) * 8 + (bid & 7);
    const int colTile = (bid >> 3) & 3;
    const int rowBase = rowTile * BM;
    const int cTile   = colTile * BN;

    const int lane  = t & 63;
    const int wv    = t >> 6;
    const int wr    = (wv >> 1) * 64;
    const int wc    = (wv & 1) * 64;
    const int lcol  = lane & 15;
    const int lquad = lane >> 4;

    // ---- B staging (r8-proven DMA scheme, B only): wave wv stages rows
    // [wv*32, wv*32+32), source chunk XOR-swizzled -> ds_read_b128 ~2-way.
    const int sRow0 = wv * 32 + (lane >> 2);
    const int sRow1 = sRow0 + 16;
    const int phys  = lane & 3;
    const int cl0   = phys ^ ((sRow0 >> 1) & 3);
    const int cl1   = phys ^ ((sRow1 >> 1) & 3);
    const unsigned short* gB0 = WmT + (size_t)(cTile + sRow0) * KD + cl0 * 8;
    const unsigned short* gB1 = WmT + (size_t)(cTile + sRow1) * KD + cl1 * 8;
    auto issueB = [&](int kt, int buf) {
        const int ko = kt * BK;
        async16(gB0 + ko, &Bs2[buf][wv * 1024]);
        async16(gB1 + ko, &Bs2[buf][wv * 1024 + 512]);
    };

    // ---- A reg staging: thread t owns row t>>1, 16 cols at (t&1)*16 ----
    const int arow = t >> 1;
    const int half = t & 1;
    const int sw   = (arow >> 1) & 3;
    const float* gA = hist_enc + (size_t)(rowBase + arow) * H + half * 16;

    auto loadA = [&](int T, float4* f) {
        f[0] = *(const float4*)(gA + T * BK);
        f[1] = *(const float4*)(gA + T * BK + 4);
        f[2] = *(const float4*)(gA + T * BK + 8);
        f[3] = *(const float4*)(gA + T * BK + 12);
    };
    auto writeA = [&](int buf, const float4* f) {
        uint4 u0, u1;
        u0.x = pk2(f[0].x, f[0].y); u0.y = pk2(f[0].z, f[0].w);
        u0.z = pk2(f[1].x, f[1].y); u0.w = pk2(f[1].z, f[1].w);
        u1.x = pk2(f[2].x, f[2].y); u1.y = pk2(f[2].z, f[2].w);
        u1.z = pk2(f[3].x, f[3].y); u1.w = pk2(f[3].z, f[3].w);
        const int c0 = half * 2;
        *(uint4*)&As2[buf][arow * BK + ((c0    ) ^ sw) * 8] = u0;
        *(uint4*)&As2[buf][arow * BK + ((c0 + 1) ^ sw) * 8] = u1;
    };
    auto embA = [&](int T, int buf) {   // emb tiles: relu(rel @ Ws + bs), Ws/bs L1-resident
        const int e0 = T * BK - H + half * 16;
        const float2 rr = relRow[arow];
        float4 f[4];
#pragma unroll
        for (int q = 0; q < 4; ++q) {
            const float4 w0 = *(const float4*)&Ws[e0 + q * 4];
            const float4 w1 = *(const float4*)&Ws[E + e0 + q * 4];
            const float4 b4 = *(const float4*)&bs[e0 + q * 4];
            f[q].x = fmaxf(rr.x * w0.x + rr.y * w1.x + b4.x, 0.f);
            f[q].y = fmaxf(rr.x * w0.y + rr.y * w1.y + b4.y, 0.f);
            f[q].z = fmaxf(rr.x * w0.z + rr.y * w1.z + b4.z, 0.f);
            f[q].w = fmaxf(rr.x * w0.w + rr.y * w1.w + b4.w, 0.f);
        }
        writeA(buf, f);
    };

    issueB(0, 0);

    // ---- prologue ----
    if (t < BM) {
        segRow[t] = segArr[rowBase + t];
        relRow[t] = *(const float2*)&relA[2 * (rowBase + t)];
    }
    if (t >= BM && t < BM + 3) bnd[t - BM] = BM;
    for (int idx = t; idx < 4 * (BN + 4); idx += 256) ((int*)Pmax)[idx] = 0;

    // tile 0: load+convert+write directly; tile 1: prefetch into regs
    float4 rA[2][4];
    loadA(0, rA[0]);
    writeA(0, rA[0]);
    loadA(1, rA[1]);

    __syncthreads();
    if (t < BM - 1) {
        const int s0 = segRow[t], s1 = segRow[t + 1];
        if (s1 != s0) bnd[s1 - segRow[0] - 1] = t + 1;   // visible after next barrier
    }

    floatx4 acc[4][4];
#pragma unroll
    for (int m = 0; m < 4; ++m)
#pragma unroll
        for (int n = 0; n < 4; ++n) acc[m][n] = (floatx4){0.f, 0.f, 0.f, 0.f};

    // ---- K loop: dist-1 B DMA dbuf + dist-2 A reg prefetch ----
    // iter kt: consume LDS buf kt&1; issue B(kt+1); prefetch A(kt+2) into
    // rA[kt&1]; after MFMA, convert rA[(kt+1)&1] (tile kt+1) -> As2[(kt+1)&1].
#pragma unroll
    for (int kt = 0; kt < NKT; ++kt) {
        __syncthreads();                       // drains B DMA(kt) + A writes(kt)
        if (kt + 1 < NKT) issueB(kt + 1, (kt + 1) & 1);
        if (kt + 2 < KH)  loadA(kt + 2, rA[kt & 1]);

        const unsigned short* A = As2[kt & 1];
        const unsigned short* B = Bs2[kt & 1];
        bf16x8 af[4], bfr[4];
#pragma unroll
        for (int mt = 0; mt < 4; ++mt) {
            const int R  = wr + mt * 16 + lcol;
            const int pc = lquad ^ ((R >> 1) & 3);
            af[mt] = *(const bf16x8*)&A[R * BK + pc * 8];
        }
#pragma unroll
        for (int nt = 0; nt < 4; ++nt) {
            const int R  = wc + nt * 16 + lcol;
            const int pc = lquad ^ ((R >> 1) & 3);
            bfr[nt] = *(const bf16x8*)&B[R * BK + pc * 8];
        }
#pragma unroll
        for (int mt = 0; mt < 4; ++mt)
#pragma unroll
            for (int nt = 0; nt < 4; ++nt)
                acc[mt][nt] = __builtin_amdgcn_mfma_f32_16x16x32_bf16(af[mt], bfr[nt], acc[mt][nt], 0, 0, 0);

        if (kt + 1 < NKT) {
            if (kt + 1 < KH) writeA((kt + 1) & 1, rA[(kt + 1) & 1]);
            else             embA(kt + 1, (kt + 1) & 1);
        }
    }

    // ---- epilogue: bias + relu + segment-max (r8-proven) ----
    const int b0 = bnd[0], b1 = bnd[1], b2 = bnd[2];
    const int segBase = segRow[0];

#pragma unroll
    for (int nt = 0; nt < 4; ++nt) {
        const int col  = wc + nt * 16 + lcol;
        const float bias = bm[cTile + col];
        float pm[4] = {0.f, 0.f, 0.f, 0.f};
#pragma unroll
        for (int mt = 0; mt < 4; ++mt) {
#pragma unroll
            for (int r = 0; r < 4; ++r) {
                const int lr = wr + mt * 16 + lquad * 4 + r;
                const int ls = (lr >= b0) + (lr >= b1) + (lr >= b2);
                const float v = fmaxf(acc[mt][nt][r] + bias, 0.f);
                pm[ls] = fmaxf(pm[ls], v);
            }
        }
#pragma unroll
        for (int ls = 0; ls < 4; ++ls)
            if (pm[ls] > 0.f)
                atomicMax(&Pmax[ls][col], __float_as_int(pm[ls]));
    }
    __syncthreads();

    for (int idx = t; idx < 4 * BN; idx += 256) {
        const int ls = idx >> 7, col = idx & 127;
        if (ls > 0 && bnd[ls - 1] >= BM) continue;
        const int seg = segBase + ls;
        const int v   = Pmax[ls][col];
        const int gs  = sse[seg], ge = sse[seg + 1];
        float* dst = &out[(size_t)seg * H + cTile + col];
        if (gs >= rowBase && ge <= rowBase + BM) {
            *dst = __int_as_float(v);
        } else {
            atomicMax((int*)dst, v);
        }
    }
}

// ---------------- fallback (round-2 kernel; only if ws too small) ----------------
constexpr int LDAF = 40;
__global__ __launch_bounds__(256) void pool_mfma_fb(
    const float* __restrict__ hist_enc, const float* __restrict__ pos,
    const int* __restrict__ sse, const float* __restrict__ Ws,
    const float* __restrict__ bs, const unsigned short* __restrict__ WmT,
    const float* __restrict__ bm, float* __restrict__ out)
{
    __shared__ __attribute__((aligned(16))) unsigned short As[BM][LDAF];
    __shared__ __attribute__((aligned(16))) unsigned short Bs[BN][LDAF];
    __shared__ float relRow[BM][2];
    __shared__ int   segRow[BM];
    __shared__ int   bnd[3];
    __shared__ int   Pmax[4][BN + 4];

    const int t = threadIdx.x;
    const int cTile = blockIdx.x * BN;
    const int rowBase = blockIdx.y * BM;

    if (t < BM) {
        const int i = rowBase + t;
        int l = 0, r = NG + 1;
        while (l < r) { int m = (l + r) >> 1; if (sse[m] <= i) l = m + 1; else r = m; }
        const int g = l - 1;
        segRow[t] = g;
        const int a = sse[g];
        relRow[t][0] = pos[2 * i + 0] - pos[2 * a + 0];
        relRow[t][1] = pos[2 * i + 1] - pos[2 * a + 1];
    }
    if (t >= BM && t < BM + 3) bnd[t - BM] = BM;
    for (int idx = t; idx < 4 * (BN + 4); idx += 256) ((int*)Pmax)[idx] = 0;
    __syncthreads();
    if (t < BM - 1) {
        const int s0 = segRow[t], s1 = segRow[t + 1];
        if (s1 != s0) bnd[s1 - segRow[0] - 1] = t + 1;
    }

    const int lane = t & 63, wv = t >> 6;
    const int wr = (wv >> 1) * 64, wc = (wv & 1) * 64;
    const int lcol = lane & 15, lquad = lane >> 4;

    floatx4 acc[4][4];
#pragma unroll
    for (int m = 0; m < 4; ++m)
#pragma unroll
        for (int n = 0; n < 4; ++n) acc[m][n] = (floatx4){0.f, 0.f, 0.f, 0.f};

    for (int kt = 0; kt < KD / BK; ++kt) {
        const int k0 = kt * BK;
        float4 av[4]; uint4 bv[2];
        if (k0 < H) {
#pragma unroll
            for (int i = 0; i < 4; ++i) {
                const int idx = i * 256 + t;
                const int row = idx >> 3, kq = (idx & 7) * 4;
                av[i] = *(const float4*)&hist_enc[(size_t)(rowBase + row) * H + k0 + kq];
            }
        } else {
#pragma unroll
            for (int i = 0; i < 4; ++i) {
                const int idx = i * 256 + t;
                const int row = idx >> 3, kq = (idx & 7) * 4;
                const int e = k0 - H + kq;
                const float4 w0 = *(const float4*)&Ws[e];
                const float4 w1 = *(const float4*)&Ws[E + e];
                const float4 b4 = *(const float4*)&bs[e];
                const float r0 = relRow[row][0], r1 = relRow[row][1];
                av[i].x = fmaxf(r0 * w0.x + r1 * w1.x + b4.x, 0.f);
                av[i].y = fmaxf(r0 * w0.y + r1 * w1.y + b4.y, 0.f);
                av[i].z = fmaxf(r0 * w0.z + r1 * w1.z + b4.z, 0.f);
                av[i].w = fmaxf(r0 * w0.w + r1 * w1.w + b4.w, 0.f);
            }
        }
#pragma unroll
        for (int i = 0; i < 2; ++i) {
            const int idx = i * 256 + t;
            const int n = idx >> 2, q = idx & 3;
            bv[i] = *(const uint4*)&WmT[(size_t)(cTile + n) * KD + k0 + q * 8];
        }
        __syncthreads();
#pragma unroll
        for (int i = 0; i < 4; ++i) {
            const int idx = i * 256 + t;
            const int row = idx >> 3, kq = (idx & 7) * 4;
            ushort4 p;
            p.x = f2bf(av[i].x); p.y = f2bf(av[i].y);
            p.z = f2bf(av[i].z); p.w = f2bf(av[i].w);
            *(ushort4*)&As[row][kq] = p;
        }
#pragma unroll
        for (int i = 0; i < 2; ++i) {
            const int idx = i * 256 + t;
            const int n = idx >> 2, q = idx & 3;
            *(uint4*)&Bs[n][q * 8] = bv[i];
        }
        __syncthreads();

        bf16x8 af[4], bfr[4];
#pragma unroll
        for (int mt = 0; mt < 4; ++mt)
            af[mt] = *(const bf16x8*)&As[wr + mt * 16 + lcol][lquad * 8];
#pragma unroll
        for (int nt = 0; nt < 4; ++nt)
            bfr[nt] = *(const bf16x8*)&Bs[wc + nt * 16 + lcol][lquad * 8];
#pragma unroll
        for (int mt = 0; mt < 4; ++mt)
#pragma unroll
            for (int nt = 0; nt < 4; ++nt)
                acc[mt][nt] = __builtin_amdgcn_mfma_f32_16x16x32_bf16(af[mt], bfr[nt], acc[mt][nt], 0, 0, 0);
    }

    const int b0 = bnd[0], b1 = bnd[1], b2 = bnd[2];
    const int segBase = segRow[0];
#pragma unroll
    for (int nt = 0; nt < 4; ++nt) {
        const int col = wc + nt * 16 + lcol;
        const float bias = bm[cTile + col];
        float pm[4] = {0.f, 0.f, 0.f, 0.f};
#pragma unroll
        for (int mt = 0; mt < 4; ++mt) {
#pragma unroll
            for (int r = 0; r < 4; ++r) {
                const int lr = wr + mt * 16 + lquad * 4 + r;
                const int ls = (lr >= b0) + (lr >= b1) + (lr >= b2);
                const float v = fmaxf(acc[mt][nt][r] + bias, 0.f);
                pm[ls] = fmaxf(pm[ls], v);
            }
        }
#pragma unroll
        for (int ls = 0; ls < 4; ++ls)
            if (pm[ls] > 0.f) atomicMax(&Pmax[ls][col], __float_as_int(pm[ls]));
    }
    __syncthreads();
    for (int idx = t; idx < 4 * BN; idx += 256) {
        const int ls = idx >> 7, col = idx & 127;
        if (ls > 0 && bnd[ls - 1] >= BM) continue;
        const int seg = segBase + ls;
        const int v = Pmax[ls][col];
        const int gs = sse[seg], ge = sse[seg + 1];
        float* dst = &out[(size_t)seg * H + cTile + col];
        if (gs >= rowBase && ge <= rowBase + BM) *dst = __int_as_float(v);
        else atomicMax((int*)dst, v);
    }
}

extern "C" void kernel_launch(void* const* d_in, const int* in_sizes, int n_in,
                              void* d_out, int out_size, void* d_ws, size_t ws_size,
                              hipStream_t stream) {
    const float* hist_enc = (const float*)d_in[0];
    const float* pos      = (const float*)d_in[1];
    const int*   sse      = (const int*)  d_in[2];
    const float* Ws       = (const float*)d_in[3];
    const float* bs       = (const float*)d_in[4];
    const float* Wm       = (const float*)d_in[5];
    const float* bm       = (const float*)d_in[6];
    float*       out      = (float*)d_out;

    const size_t needWmT = (size_t)H * KD * 2;     // 655,360 B
    const size_t needSeg = (size_t)NR * 4;         // 409,600 B
    const size_t needRel = (size_t)NR * 2 * 4;     // 819,200 B
    unsigned short* WmT  = (unsigned short*)d_ws;
    int*            segA = (int*)  ((char*)d_ws + needWmT);
    float*          relA = (float*)((char*)d_ws + needWmT + needSeg);

    hipMemsetAsync(out, 0, (size_t)out_size * sizeof(float), stream);

    if (ws_size >= needWmT + needSeg + needRel) {
        prep3<<<480, 256, 0, stream>>>(pos, sse, Wm, WmT, segA, relA);
        pool_fused2<<<3200, 256, 0, stream>>>(hist_enc, sse, segA, relA, Ws, bs, WmT, bm, out);
    } else {
        prep3<<<480, 256, 0, stream>>>(pos, sse, Wm, WmT, nullptr, nullptr);
        pool_mfma_fb<<<dim3(H / BN, NR / BM), 256, 0, stream>>>(hist_enc, pos, sse, Ws, bs, WmT, bm, out);
    }
}